// Round 1
// baseline (55631.506 us; speedup 1.0000x reference)
//
#include <hip/hip_runtime.h>
#include <hip/hip_bf16.h>

// ---------------- problem constants ----------------
constexpr int Bn = 64;
constexpr int Tn = 512;
constexpr int Hn = 512;
constexpr int DINn = 6;
constexpr int NG = 2048;          // 4*H gate columns

constexpr size_t BH = (size_t)Bn * Hn;          // 32768
constexpr size_t BIG = (size_t)Bn * Tn * Hn;    // 16777216

// ws layout (in floats)
constexpr size_t NH1_OFF  = 0;            // [2][B][H] unblended layer1 outputs (ping-pong)
constexpr size_t H1S_OFF  = 2 * BH;       // [2][B][H] blended h1 state
constexpr size_t H2S_OFF  = 4 * BH;       // [2][B][H] blended h2 state
constexpr size_t C1_OFF   = 6 * BH;       // [B][H]
constexpr size_t C2_OFF   = 7 * BH;       // [B][H]
constexpr size_t H2ALL_OFF = 8 * BH;      // [B*T][H]  (m * nh2) ; reused as X2
constexpr size_t X1_OFF   = H2ALL_OFF + BIG; // [B*T][512] ; reused as X3
constexpr size_t WS_FLOATS = X1_OFF + BIG;   // 33,816,576 floats = 135.3 MB

__device__ __forceinline__ float sigmoidf_(float x) { return 1.f / (1.f + expf(-x)); }

// ---------------- recurrence step ----------------
// Launch t (0..T inclusive):
//   blocks [0,128)  : layer1, computes nh1(t), c1(t), h1state(t)     (active t < T)
//   blocks [128,256): layer2, computes h2state(t-1), c2(t-1), h2_all (active t >= 1)
// Block covers 4 h-dims x all 64 batch rows. 512 threads = (b 64) x (gate q 4) x (k-half 2).
__global__ __launch_bounds__(512) void step_kernel(
    const float* __restrict__ seq_in, const int* __restrict__ lens,
    const float* __restrict__ W1, const float* __restrict__ b1,
    const float* __restrict__ W2, const float* __restrict__ b2,
    float* __restrict__ ws, int t)
{
    __shared__ float lds[64][65];     // [k-in-chunk][b], padded
    __shared__ float ex[4][4][64];    // [gate][dim-sub][b]

    const int tid = threadIdx.x;
    const int b  = tid & 63;
    const int q  = (tid >> 6) & 3;
    const int kh = tid >> 8;
    const bool isL1 = (blockIdx.x < 128);

    if (isL1) { if (t >= Tn) return; }
    else      { if (t < 1)  return; }

    const int s  = t - 1;                       // layer2 step index
    const int d0 = (isL1 ? blockIdx.x : (blockIdx.x - 128)) * 4;
    const int qd = q * Hn + d0;

    const float* W  = isL1 ? W1 : W2;
    const float* bs = isL1 ? b1 : b2;

    const float* srcL1 = ws + H1S_OFF + (size_t)((t + 1) & 1) * BH;  // h1 state (t-1)
    const float* srcN1 = ws + NH1_OFF + (size_t)(s & 1) * BH;        // nh1(s)
    const float* srcH2 = ws + H2S_OFF + (size_t)((s + 1) & 1) * BH;  // h2 state (s-1)

    float a0 = 0.f, a1 = 0.f, a2 = 0.f, a3 = 0.f;

    // x-part of layer1 (rows 0..5 of W1), only k-half 0
    if (isL1 && kh == 0) {
        const float* xp = seq_in + ((size_t)b * Tn + t) * DINn;
        #pragma unroll
        for (int k = 0; k < DINn; ++k) {
            const float4 w = *reinterpret_cast<const float4*>(W1 + (size_t)k * NG + qd);
            const float xv = xp[k];
            a0 += xv * w.x; a1 += xv * w.y; a2 += xv * w.z; a3 += xv * w.w;
        }
    }

    const int nch = isL1 ? 8 : 16;
    const int khshift = isL1 ? 2 : 3;

    for (int cc = 0; cc < nch; ++cc) {
        const float* src; int eb;
        if (isL1)        { src = srcL1; eb = cc * 64; }
        else if (cc < 8) { src = srcN1; eb = cc * 64; }
        else             { src = srcH2; eb = (cc - 8) * 64; }
        // stage 64(k) x 64(b) chunk, transposed into LDS
        for (int i = tid; i < 4096; i += 512)
            lds[i & 63][i >> 6] = src[(size_t)(i >> 6) * Hn + eb + (i & 63)];
        __syncthreads();
        if ((cc >> khshift) == kh) {
            const int row0 = isL1 ? (DINn + cc * 64) : (cc * 64);
            const float* wp = W + (size_t)row0 * NG + qd;
            #pragma unroll 4
            for (int kk = 0; kk < 64; ++kk) {
                const float hv = lds[kk][b];
                const float4 w = *reinterpret_cast<const float4*>(wp + (size_t)kk * NG);
                a0 += hv * w.x; a1 += hv * w.y; a2 += hv * w.z; a3 += hv * w.w;
            }
        }
        __syncthreads();
    }

    // reduce k-halves, add bias
    if (kh == 1) { ex[q][0][b] = a0; ex[q][1][b] = a1; ex[q][2][b] = a2; ex[q][3][b] = a3; }
    __syncthreads();
    if (kh == 0) {
        ex[q][0][b] = a0 + ex[q][0][b] + bs[qd + 0];
        ex[q][1][b] = a1 + ex[q][1][b] + bs[qd + 1];
        ex[q][2][b] = a2 + ex[q][2][b] + bs[qd + 2];
        ex[q][3][b] = a3 + ex[q][3][b] + bs[qd + 3];
    }
    __syncthreads();
    // state update: thread (b, q) owns dim d = d0+q
    if (kh == 0) {
        const int d = d0 + q;
        const float gi = ex[0][q][b];
        const float gj = ex[1][q][b];
        const float gf = ex[2][q][b];
        const float go = ex[3][q][b];
        const int stepidx = isL1 ? t : s;
        const float m = (stepidx < lens[b]) ? 1.f : 0.f;
        const size_t ci = (isL1 ? C1_OFF : C2_OFF) + (size_t)b * Hn + d;
        const float cold = ws[ci];
        const float cnew = cold * sigmoidf_(gf + 1.f) + sigmoidf_(gi) * tanhf(gj);
        ws[ci] = m * cnew + (1.f - m) * cold;
        const float nh = tanhf(cnew) * sigmoidf_(go);
        if (isL1) {
            ws[NH1_OFF + (size_t)(t & 1) * BH + (size_t)b * Hn + d] = nh;
            const float hold = srcL1[(size_t)b * Hn + d];
            ws[H1S_OFF + (size_t)(t & 1) * BH + (size_t)b * Hn + d] = m * nh + (1.f - m) * hold;
        } else {
            const float hold = srcH2[(size_t)b * Hn + d];
            ws[H2S_OFF + (size_t)(s & 1) * BH + (size_t)b * Hn + d] = m * nh + (1.f - m) * hold;
            ws[H2ALL_OFF + ((size_t)b * Tn + s) * Hn + d] = m * nh;
        }
    }
}

// ---------------- dense GEMM: C = relu?(A[M,K] @ W[K,N] + bias) ----------------
// 128x128 tile per 256-thread block, 8x8 micro-tile, k-chunk 16.
__global__ __launch_bounds__(256) void gemm_relu_kernel(
    const float* __restrict__ A, const float* __restrict__ W,
    const float* __restrict__ bias, float* __restrict__ C,
    int M, int N, int K, int relu)
{
    __shared__ float As[16][132];
    __shared__ float Bs[16][128];
    const int tid = threadIdx.x;
    const int tx = tid & 15, ty = tid >> 4;
    const int rbase = blockIdx.y * 128, cbase = blockIdx.x * 128;

    float acc[8][8] = {};
    for (int k0 = 0; k0 < K; k0 += 16) {
        #pragma unroll
        for (int u = 0; u < 2; ++u) {           // stage A (transposed)
            const int idx4 = u * 256 + tid;
            const int kk4 = idx4 & 3, rr = idx4 >> 2;
            const float4 v = *reinterpret_cast<const float4*>(
                A + (size_t)(rbase + rr) * K + k0 + kk4 * 4);
            As[kk4 * 4 + 0][rr] = v.x; As[kk4 * 4 + 1][rr] = v.y;
            As[kk4 * 4 + 2][rr] = v.z; As[kk4 * 4 + 3][rr] = v.w;
        }
        #pragma unroll
        for (int u = 0; u < 2; ++u) {           // stage B
            const int idx4 = u * 256 + tid;
            const int cc4 = idx4 & 31, kk = idx4 >> 5;
            *reinterpret_cast<float4*>(&Bs[kk][cc4 * 4]) =
                *reinterpret_cast<const float4*>(W + (size_t)(k0 + kk) * N + cbase + cc4 * 4);
        }
        __syncthreads();
        #pragma unroll
        for (int kk = 0; kk < 16; ++kk) {
            const float4 A0 = *reinterpret_cast<const float4*>(&As[kk][ty * 8]);
            const float4 A1 = *reinterpret_cast<const float4*>(&As[kk][ty * 8 + 4]);
            const float4 B0 = *reinterpret_cast<const float4*>(&Bs[kk][tx * 8]);
            const float4 B1 = *reinterpret_cast<const float4*>(&Bs[kk][tx * 8 + 4]);
            const float av[8] = {A0.x, A0.y, A0.z, A0.w, A1.x, A1.y, A1.z, A1.w};
            const float bv[8] = {B0.x, B0.y, B0.z, B0.w, B1.x, B1.y, B1.z, B1.w};
            #pragma unroll
            for (int i = 0; i < 8; ++i)
                #pragma unroll
                for (int j = 0; j < 8; ++j) acc[i][j] += av[i] * bv[j];
        }
        __syncthreads();
    }
    float bvs[8];
    #pragma unroll
    for (int j = 0; j < 8; ++j) bvs[j] = bias[cbase + tx * 8 + j];
    #pragma unroll
    for (int i = 0; i < 8; ++i) {
        const int r = rbase + ty * 8 + i;
        float o[8];
        #pragma unroll
        for (int j = 0; j < 8; ++j) {
            float v = acc[i][j] + bvs[j];
            o[j] = relu ? fmaxf(v, 0.f) : v;
        }
        float4* p = reinterpret_cast<float4*>(C + (size_t)r * N + cbase + tx * 8);
        p[0] = make_float4(o[0], o[1], o[2], o[3]);
        p[1] = make_float4(o[4], o[5], o[6], o[7]);
    }
}

// ---------------- final tiny layer: out = X3[M,256] @ Wd4[256,4] + bd4 ----------------
__global__ __launch_bounds__(256) void d4_kernel(
    const float* __restrict__ X3, const float* __restrict__ W,
    const float* __restrict__ bias, float* __restrict__ out)
{
    const int lane = threadIdx.x & 63;
    const int rr = threadIdx.x >> 6;
    const size_t r = (size_t)blockIdx.x * 4 + rr;
    float p0 = 0, p1 = 0, p2 = 0, p3 = 0;
    #pragma unroll
    for (int j = 0; j < 4; ++j) {
        const int k = j * 64 + lane;
        const float x = X3[r * 256 + k];
        const float4 w = *reinterpret_cast<const float4*>(W + (size_t)k * 4);
        p0 += x * w.x; p1 += x * w.y; p2 += x * w.z; p3 += x * w.w;
    }
    #pragma unroll
    for (int off = 32; off > 0; off >>= 1) {
        p0 += __shfl_down(p0, off); p1 += __shfl_down(p1, off);
        p2 += __shfl_down(p2, off); p3 += __shfl_down(p3, off);
    }
    if (lane == 0) {
        *reinterpret_cast<float4*>(out + r * 4) =
            make_float4(p0 + bias[0], p1 + bias[1], p2 + bias[2], p3 + bias[3]);
    }
}

// ---------------- masked sequence MSE ----------------
__global__ __launch_bounds__(256) void loss_kernel(
    const float* __restrict__ out, const float* __restrict__ tgt,
    const int* __restrict__ lens, float* __restrict__ lossp)
{
    __shared__ float red[256];
    float acc = 0.f;
    for (int idx = threadIdx.x; idx < Bn * Tn; idx += 256) {
        const int b = idx >> 9;  // T = 512
        const float4 o = *reinterpret_cast<const float4*>(out + (size_t)idx * 4);
        const float4 g = *reinterpret_cast<const float4*>(tgt + (size_t)idx * 4);
        const float dx = o.x - g.x, dy = o.y - g.y, dz = o.z - g.z, dw = o.w - g.w;
        const float fm = 0.25f * (dx * dx + dy * dy + dz * dz + dw * dw);
        const float ma = fmaxf(fmaxf(fabsf(g.x), fabsf(g.y)), fmaxf(fabsf(g.z), fabsf(g.w)));
        const float mask = (ma > 0.f) ? 1.f : 0.f;
        acc += fm * mask / ((float)lens[b] * 64.f);
    }
    red[threadIdx.x] = acc;
    __syncthreads();
    for (int st = 128; st > 0; st >>= 1) {
        if (threadIdx.x < st) red[threadIdx.x] += red[threadIdx.x + st];
        __syncthreads();
    }
    if (threadIdx.x == 0) *lossp = red[0];
}

__global__ void init_kernel(float* __restrict__ ws)
{
    const size_t n = 8 * BH;  // all state buffers
    for (size_t i = (size_t)blockIdx.x * 256 + threadIdx.x; i < n; i += (size_t)gridDim.x * 256)
        ws[i] = 0.f;
}

__global__ void sentinel_kernel(float* __restrict__ out, int n)
{
    for (int i = blockIdx.x * 256 + threadIdx.x; i < n; i += gridDim.x * 256)
        out[i] = 1.0e9f;  // unambiguous "ws too small" signal
}

extern "C" void kernel_launch(void* const* d_in, const int* in_sizes, int n_in,
                              void* d_out, int out_size, void* d_ws, size_t ws_size,
                              hipStream_t stream)
{
    const float* seq_in = (const float*)d_in[0];
    const float* tgt    = (const float*)d_in[1];
    const int*   lens   = (const int*)d_in[2];
    const float* W1  = (const float*)d_in[3];
    const float* b1  = (const float*)d_in[4];
    const float* W2  = (const float*)d_in[5];
    const float* b2  = (const float*)d_in[6];
    const float* Wd1 = (const float*)d_in[7];
    const float* bd1 = (const float*)d_in[8];
    const float* Wd2 = (const float*)d_in[9];
    const float* bd2 = (const float*)d_in[10];
    const float* Wd3 = (const float*)d_in[11];
    const float* bd3 = (const float*)d_in[12];
    const float* Wd4 = (const float*)d_in[13];
    const float* bd4 = (const float*)d_in[14];
    float* out = (float*)d_out;
    float* ws  = (float*)d_ws;

    if (ws_size < WS_FLOATS * sizeof(float)) {
        hipLaunchKernelGGL(sentinel_kernel, dim3(256), dim3(256), 0, stream, out, out_size);
        return;
    }

    hipLaunchKernelGGL(init_kernel, dim3(256), dim3(256), 0, stream, ws);

    for (int t = 0; t <= Tn; ++t)
        hipLaunchKernelGGL(step_kernel, dim3(256), dim3(512), 0, stream,
                           seq_in, lens, W1, b1, W2, b2, ws, t);

    float* h2all = ws + H2ALL_OFF;
    float* X1 = ws + X1_OFF;
    float* X2 = h2all;   // h2all dead after D1
    float* X3 = X1;      // X1 dead after D2

    hipLaunchKernelGGL(gemm_relu_kernel, dim3(4, 256), dim3(256), 0, stream,
                       h2all, Wd1, bd1, X1, Bn * Tn, 512, 512, 1);
    hipLaunchKernelGGL(gemm_relu_kernel, dim3(4, 256), dim3(256), 0, stream,
                       X1, Wd2, bd2, X2, Bn * Tn, 512, 512, 1);
    hipLaunchKernelGGL(gemm_relu_kernel, dim3(2, 256), dim3(256), 0, stream,
                       X2, Wd3, bd3, X3, Bn * Tn, 256, 512, 1);
    hipLaunchKernelGGL(d4_kernel, dim3((Bn * Tn) / 4), dim3(256), 0, stream,
                       X3, Wd4, bd4, out);
    hipLaunchKernelGGL(loss_kernel, dim3(1), dim3(256), 0, stream,
                       out, tgt, lens, out + (size_t)Bn * Tn * 4);
}

// Round 2
// 5642.816 us; speedup vs baseline: 9.8588x; 9.8588x over previous
//
#include <hip/hip_runtime.h>
#include <hip/hip_bf16.h>

// ---------------- problem constants ----------------
constexpr int Bn = 64;
constexpr int Tn = 512;
constexpr int Hn = 512;

using bf16x8 = __attribute__((ext_vector_type(8))) short;
using f32x4  = __attribute__((ext_vector_type(4))) float;

// ---------------- ws layout (byte offsets) ----------------
// A1: bf16 [2][64][512]   blended h1 state (ping-pong)
// A2: bf16 [2][64][1024]  cols 0..511 = nh1 (unblended), 512..1023 = blended h2 state
// C1/C2: f32 [64][512]
// BIASP: f32 [2][2048] gate-permuted biases
// H2ALL: f32 [64*512][512]  (m*nh2), head input; reused as X2
// X1: f32 region 64 MB (head intermediates); W/XPAD buffers overlap its start
constexpr size_t OFF_A1    = 0;
constexpr size_t OFF_A2    = OFF_A1 + (size_t)2*64*512*2;      // 131072
constexpr size_t OFF_C1    = OFF_A2 + (size_t)2*64*1024*2;     // 393216
constexpr size_t OFF_C2    = OFF_C1 + (size_t)64*512*4;        // 524288
constexpr size_t OFF_BIASP = OFF_C2 + (size_t)64*512*4;        // 655360
constexpr size_t OFF_H2ALL = OFF_BIASP + (size_t)2*2048*4;     // 671744
constexpr size_t OFF_X1    = OFF_H2ALL + (size_t)64*512*512*4; // 67780608
constexpr size_t OFF_XPAD  = OFF_X1;                            // bf16 [512][64][32] = 2 MB
constexpr size_t OFF_W1P   = OFF_XPAD + (size_t)512*64*32*2;    // bf16 [64][17][2][64][8]
constexpr size_t OFF_W2P   = OFF_W1P + (size_t)64*17*2*64*8*2;  // bf16 [64][32][2][64][8]
constexpr size_t WS_NEED   = OFF_X1 + (size_t)64*512*512*4;     // 134,889,472 B

__device__ __forceinline__ float sigf(float x) { return 1.f / (1.f + expf(-x)); }
__device__ __forceinline__ unsigned short f2b(float x) {
    __hip_bfloat16 h = __float2bfloat16(x);
    return *reinterpret_cast<unsigned short*>(&h);
}
__device__ __forceinline__ float b2f(unsigned short u) {
    __hip_bfloat16 h = *reinterpret_cast<__hip_bfloat16*>(&u);
    return __bfloat162float(h);
}

// ---------------- one-time prep: swizzle W to MFMA frag order, pad x, zero state ----------------
// Gate-permuted columns: colg in [0,2048): d = colg>>2, g = colg&3, orig col = g*512 + d.
// W*P element [np][kk][half][lane][j] = W[k = kk*32 + (lane>>4)*8 + j][orig(colg)],
//   colg = (np*2+half)*16 + (lane&15).
constexpr int PN0 = 64*17*2*64;            // W1P ushort8 items   = 139264
constexpr int PN1 = PN0 + 64*32*2*64;      // W2P items           = 401408
constexpr int PN2 = PN1 + 4096;            // BIASP f32 items     = 405504
constexpr int PN3 = PN2 + 512*64*4;        // XPAD ushort8 items  = 536576
constexpr int PN4 = PN3 + 24576;           // zero A1+A2 ushort8  = 561152
constexpr int PN5 = PN4 + 16384;           // zero C1+C2 float4   = 577536

__global__ __launch_bounds__(256) void prep_kernel(
    const float* __restrict__ seq_in,
    const float* __restrict__ W1, const float* __restrict__ b1,
    const float* __restrict__ W2, const float* __restrict__ b2,
    char* __restrict__ ws)
{
    const int idx = blockIdx.x * 256 + threadIdx.x;
    if (idx >= PN5) return;
    if (idx < PN0) {                       // W1P (K = 512 h-part as kk 0..15, x-part kk==16)
        const int lane = idx & 63; int r = idx >> 6;
        const int half = r & 1; r >>= 1;
        const int kk = r % 17, np = r / 17;
        const int colg = (np*2 + half)*16 + (lane & 15);
        const int oc = (colg & 3)*512 + (colg >> 2);
        const int lg = lane >> 4;
        short v[8];
        #pragma unroll
        for (int j = 0; j < 8; ++j) {
            float x;
            if (kk < 16) x = W1[(size_t)(6 + kk*32 + lg*8 + j) * 2048 + oc];
            else { const int rr = lg*8 + j; x = (rr < 6) ? W1[(size_t)rr * 2048 + oc] : 0.f; }
            v[j] = (short)f2b(x);
        }
        bf16x8* dst = (bf16x8*)((unsigned short*)(ws + OFF_W1P) + ((size_t)(np*17 + kk)*2 + half)*512 + lane*8);
        *dst = *(bf16x8*)v;
    } else if (idx < PN1) {                // W2P (K = 1024)
        const int i = idx - PN0;
        const int lane = i & 63; int r = i >> 6;
        const int half = r & 1; r >>= 1;
        const int kk = r & 31, np = r >> 5;
        const int colg = (np*2 + half)*16 + (lane & 15);
        const int oc = (colg & 3)*512 + (colg >> 2);
        const int lg = lane >> 4;
        short v[8];
        #pragma unroll
        for (int j = 0; j < 8; ++j)
            v[j] = (short)f2b(W2[(size_t)(kk*32 + lg*8 + j) * 2048 + oc]);
        bf16x8* dst = (bf16x8*)((unsigned short*)(ws + OFF_W2P) + ((size_t)(np*32 + kk)*2 + half)*512 + lane*8);
        *dst = *(bf16x8*)v;
    } else if (idx < PN2) {                // BIASP
        const int i = idx - PN1;
        const int layer = i >> 11, colg = i & 2047;
        const float* bb = layer ? b2 : b1;
        ((float*)(ws + OFF_BIASP))[i] = bb[(colg & 3)*512 + (colg >> 2)];
    } else if (idx < PN3) {                // XPAD [t][b][32], x in cols 0..5
        const int i = idx - PN2;
        const int sub = i & 3, tb = i >> 2;
        const int t = tb >> 6, b = tb & 63;
        short v[8];
        #pragma unroll
        for (int j = 0; j < 8; ++j) {
            const int rr = sub*8 + j;
            v[j] = (short)f2b(rr < 6 ? seq_in[((size_t)b*Tn + t)*6 + rr] : 0.f);
        }
        bf16x8* dst = (bf16x8*)((unsigned short*)(ws + OFF_XPAD) + (size_t)tb*32 + sub*8);
        *dst = *(bf16x8*)v;
    } else if (idx < PN4) {                // zero A1 + A2
        const int i = idx - PN3;
        bf16x8 z = {};
        ((bf16x8*)((unsigned short*)(ws + OFF_A1)))[i] = z;
    } else {                               // zero C1 + C2
        const int i = idx - PN4;
        ((float4*)(ws + OFF_C1))[i] = make_float4(0.f, 0.f, 0.f, 0.f);
    }
}

// ---------------- recurrence step ----------------
// Launch t in [0,512]. 512 single-wave blocks:
//   blocks [0,256)  : L1 task (computes nh1(t), c1(t), h1state(t)),      active t < 512
//   blocks [256,512): L2 task (computes h2state(t-1), c2(t-1), h2_all),  active t >= 1
// Each wave: C tile = 16 batch rows x 32 gate-cols (= 8 h-dims x 4 gates).
__global__ __launch_bounds__(64) void step_kernel(const int* __restrict__ lens,
                                                  char* __restrict__ ws, int t)
{
    __shared__ float sc[16][33];
    const int l = threadIdx.x;
    const int w = blockIdx.x;
    const bool isL1 = (w < 256);
    if (isL1) { if (t >= Tn) return; } else { if (t < 1) return; }
    const int v = isL1 ? w : w - 256;
    const int mt = v & 3, np = v >> 2;      // mt: batch 16-row tile, np: 32-col group
    const int s = t - 1;
    const int lr = l & 15, lg = l >> 4;

    const unsigned short* A1prev = (const unsigned short*)(ws + OFF_A1) + (size_t)((t+1)&1)*(64*512);
    unsigned short*       A1cur  = (unsigned short*)(ws + OFF_A1)       + (size_t)(t&1)*(64*512);
    const unsigned short* A2prev = (const unsigned short*)(ws + OFF_A2) + (size_t)((t+1)&1)*(64*1024);
    unsigned short*       A2cur  = (unsigned short*)(ws + OFF_A2)       + (size_t)(t&1)*(64*1024);
    float* C1f = (float*)(ws + OFF_C1);
    float* C2f = (float*)(ws + OFF_C2);
    const float* biasp = (const float*)(ws + OFF_BIASP);
    float* h2all = (float*)(ws + OFF_H2ALL);

    f32x4 acc0 = {0.f,0.f,0.f,0.f}, acc1 = {0.f,0.f,0.f,0.f};

    if (isL1) {
        const unsigned short* Ap = A1prev + (mt*16 + lr)*512 + lg*8;
        const unsigned short* Bp = (const unsigned short*)(ws + OFF_W1P) + (size_t)(np*17*2)*512 + l*8;
        #pragma unroll 4
        for (int kk = 0; kk < 16; ++kk) {
            bf16x8 a  = *(const bf16x8*)(Ap + kk*32);
            bf16x8 b0 = *(const bf16x8*)(Bp + (kk*2+0)*512);
            bf16x8 b1 = *(const bf16x8*)(Bp + (kk*2+1)*512);
            acc0 = __builtin_amdgcn_mfma_f32_16x16x32_bf16(a, b0, acc0, 0, 0, 0);
            acc1 = __builtin_amdgcn_mfma_f32_16x16x32_bf16(a, b1, acc1, 0, 0, 0);
        }
        const unsigned short* XP = (const unsigned short*)(ws + OFF_XPAD);
        bf16x8 a  = *(const bf16x8*)(XP + ((size_t)t*64 + mt*16 + lr)*32 + lg*8);
        bf16x8 b0 = *(const bf16x8*)(Bp + (16*2+0)*512);
        bf16x8 b1 = *(const bf16x8*)(Bp + (16*2+1)*512);
        acc0 = __builtin_amdgcn_mfma_f32_16x16x32_bf16(a, b0, acc0, 0, 0, 0);
        acc1 = __builtin_amdgcn_mfma_f32_16x16x32_bf16(a, b1, acc1, 0, 0, 0);
    } else {
        const unsigned short* Ap = A2prev + (mt*16 + lr)*1024 + lg*8;
        const unsigned short* Bp = (const unsigned short*)(ws + OFF_W2P) + (size_t)(np*32*2)*512 + l*8;
        #pragma unroll 8
        for (int kk = 0; kk < 32; ++kk) {
            bf16x8 a  = *(const bf16x8*)(Ap + kk*32);
            bf16x8 b0 = *(const bf16x8*)(Bp + (kk*2+0)*512);
            bf16x8 b1 = *(const bf16x8*)(Bp + (kk*2+1)*512);
            acc0 = __builtin_amdgcn_mfma_f32_16x16x32_bf16(a, b0, acc0, 0, 0, 0);
            acc1 = __builtin_amdgcn_mfma_f32_16x16x32_bf16(a, b1, acc1, 0, 0, 0);
        }
    }

    // bias + gate exchange through wave-local LDS (no barrier: single wave)
    const int layer = isL1 ? 0 : 1;
    const float bb0 = biasp[layer*2048 + np*32 + lr];
    const float bb1 = biasp[layer*2048 + np*32 + 16 + lr];
    #pragma unroll
    for (int i = 0; i < 4; ++i) {
        sc[lg*4 + i][lr]      = acc0[i] + bb0;
        sc[lg*4 + i][16 + lr] = acc1[i] + bb1;
    }
    asm volatile("s_waitcnt lgkmcnt(0)" ::: "memory");

    // state update: lane handles (b = mt*16+lr, d = np*8 + {lg, lg+4})
    const int b = mt*16 + lr;
    const int stepidx = isL1 ? t : s;
    const float m = (stepidx < lens[b]) ? 1.f : 0.f;
    #pragma unroll
    for (int pp = 0; pp < 2; ++pp) {
        const int dsub = lg + pp*4;
        const int d = np*8 + dsub;
        const float gi = sc[lr][dsub*4 + 0];
        const float gj = sc[lr][dsub*4 + 1];
        const float gf = sc[lr][dsub*4 + 2];
        const float go = sc[lr][dsub*4 + 3];
        const float sgf = sigf(gf + 1.f);
        const float sgi = sigf(gi);
        const float sgo = sigf(go);
        const float tj  = tanhf(gj);
        if (isL1) {
            const float cold = C1f[b*512 + d];
            const float cnew = cold*sgf + sgi*tj;
            C1f[b*512 + d] = m*cnew + (1.f - m)*cold;
            const float nh = tanhf(cnew)*sgo;
            A2cur[b*1024 + d] = f2b(nh);                       // nh1 (unblended) -> L2 input
            const float hold = b2f(A1prev[b*512 + d]);
            A1cur[b*512 + d] = f2b(m*nh + (1.f - m)*hold);     // blended h1 state
        } else {
            const float cold = C2f[b*512 + d];
            const float cnew = cold*sgf + sgi*tj;
            C2f[b*512 + d] = m*cnew + (1.f - m)*cold;
            const float nh = tanhf(cnew)*sgo;
            const float hold = b2f(A2prev[b*1024 + 512 + d]);
            A2cur[b*1024 + 512 + d] = f2b(m*nh + (1.f - m)*hold);  // blended h2 state
            h2all[((size_t)b*Tn + s)*512 + d] = m*nh;              // f32 head input
        }
    }
}

// ---------------- dense GEMM: C = relu?(A[M,K] @ W[K,N] + bias) (f32, validated) ----------------
__global__ __launch_bounds__(256) void gemm_relu_kernel(
    const float* __restrict__ A, const float* __restrict__ W,
    const float* __restrict__ bias, float* __restrict__ C,
    int M, int N, int K, int relu)
{
    __shared__ float As[16][132];
    __shared__ float Bs[16][128];
    const int tid = threadIdx.x;
    const int tx = tid & 15, ty = tid >> 4;
    const int rbase = blockIdx.y * 128, cbase = blockIdx.x * 128;

    float acc[8][8] = {};
    for (int k0 = 0; k0 < K; k0 += 16) {
        #pragma unroll
        for (int u = 0; u < 2; ++u) {
            const int idx4 = u * 256 + tid;
            const int kk4 = idx4 & 3, rr = idx4 >> 2;
            const float4 v = *reinterpret_cast<const float4*>(
                A + (size_t)(rbase + rr) * K + k0 + kk4 * 4);
            As[kk4 * 4 + 0][rr] = v.x; As[kk4 * 4 + 1][rr] = v.y;
            As[kk4 * 4 + 2][rr] = v.z; As[kk4 * 4 + 3][rr] = v.w;
        }
        #pragma unroll
        for (int u = 0; u < 2; ++u) {
            const int idx4 = u * 256 + tid;
            const int cc4 = idx4 & 31, kk = idx4 >> 5;
            *reinterpret_cast<float4*>(&Bs[kk][cc4 * 4]) =
                *reinterpret_cast<const float4*>(W + (size_t)(k0 + kk) * N + cbase + cc4 * 4);
        }
        __syncthreads();
        #pragma unroll
        for (int kk = 0; kk < 16; ++kk) {
            const float4 A0 = *reinterpret_cast<const float4*>(&As[kk][ty * 8]);
            const float4 A1 = *reinterpret_cast<const float4*>(&As[kk][ty * 8 + 4]);
            const float4 B0 = *reinterpret_cast<const float4*>(&Bs[kk][tx * 8]);
            const float4 B1 = *reinterpret_cast<const float4*>(&Bs[kk][tx * 8 + 4]);
            const float av[8] = {A0.x, A0.y, A0.z, A0.w, A1.x, A1.y, A1.z, A1.w};
            const float bv[8] = {B0.x, B0.y, B0.z, B0.w, B1.x, B1.y, B1.z, B1.w};
            #pragma unroll
            for (int i = 0; i < 8; ++i)
                #pragma unroll
                for (int j = 0; j < 8; ++j) acc[i][j] += av[i] * bv[j];
        }
        __syncthreads();
    }
    float bvs[8];
    #pragma unroll
    for (int j = 0; j < 8; ++j) bvs[j] = bias[cbase + tx * 8 + j];
    #pragma unroll
    for (int i = 0; i < 8; ++i) {
        const int r = rbase + ty * 8 + i;
        float o[8];
        #pragma unroll
        for (int j = 0; j < 8; ++j) {
            float v = acc[i][j] + bvs[j];
            o[j] = relu ? fmaxf(v, 0.f) : v;
        }
        float4* p = reinterpret_cast<float4*>(C + (size_t)r * N + cbase + tx * 8);
        p[0] = make_float4(o[0], o[1], o[2], o[3]);
        p[1] = make_float4(o[4], o[5], o[6], o[7]);
    }
}

// ---------------- final tiny layer ----------------
__global__ __launch_bounds__(256) void d4_kernel(
    const float* __restrict__ X3, const float* __restrict__ W,
    const float* __restrict__ bias, float* __restrict__ out)
{
    const int lane = threadIdx.x & 63;
    const int rr = threadIdx.x >> 6;
    const size_t r = (size_t)blockIdx.x * 4 + rr;
    float p0 = 0, p1 = 0, p2 = 0, p3 = 0;
    #pragma unroll
    for (int j = 0; j < 4; ++j) {
        const int k = j * 64 + lane;
        const float x = X3[r * 256 + k];
        const float4 w = *reinterpret_cast<const float4*>(W + (size_t)k * 4);
        p0 += x * w.x; p1 += x * w.y; p2 += x * w.z; p3 += x * w.w;
    }
    #pragma unroll
    for (int off = 32; off > 0; off >>= 1) {
        p0 += __shfl_down(p0, off); p1 += __shfl_down(p1, off);
        p2 += __shfl_down(p2, off); p3 += __shfl_down(p3, off);
    }
    if (lane == 0) {
        *reinterpret_cast<float4*>(out + r * 4) =
            make_float4(p0 + bias[0], p1 + bias[1], p2 + bias[2], p3 + bias[3]);
    }
}

// ---------------- masked sequence MSE ----------------
__global__ __launch_bounds__(256) void loss_kernel(
    const float* __restrict__ out, const float* __restrict__ tgt,
    const int* __restrict__ lens, float* __restrict__ lossp)
{
    __shared__ float red[256];
    float acc = 0.f;
    for (int idx = threadIdx.x; idx < Bn * Tn; idx += 256) {
        const int b = idx >> 9;  // T = 512
        const float4 o = *reinterpret_cast<const float4*>(out + (size_t)idx * 4);
        const float4 g = *reinterpret_cast<const float4*>(tgt + (size_t)idx * 4);
        const float dx = o.x - g.x, dy = o.y - g.y, dz = o.z - g.z, dw = o.w - g.w;
        const float fm = 0.25f * (dx * dx + dy * dy + dz * dz + dw * dw);
        const float ma = fmaxf(fmaxf(fabsf(g.x), fabsf(g.y)), fmaxf(fabsf(g.z), fabsf(g.w)));
        const float mask = (ma > 0.f) ? 1.f : 0.f;
        acc += fm * mask / ((float)lens[b] * 64.f);
    }
    red[threadIdx.x] = acc;
    __syncthreads();
    for (int st = 128; st > 0; st >>= 1) {
        if (threadIdx.x < st) red[threadIdx.x] += red[threadIdx.x + st];
        __syncthreads();
    }
    if (threadIdx.x == 0) *lossp = red[0];
}

__global__ void sentinel_kernel(float* __restrict__ out, int n)
{
    for (int i = blockIdx.x * 256 + threadIdx.x; i < n; i += gridDim.x * 256)
        out[i] = 1.0e9f;
}

extern "C" void kernel_launch(void* const* d_in, const int* in_sizes, int n_in,
                              void* d_out, int out_size, void* d_ws, size_t ws_size,
                              hipStream_t stream)
{
    const float* seq_in = (const float*)d_in[0];
    const float* tgt    = (const float*)d_in[1];
    const int*   lens   = (const int*)d_in[2];
    const float* W1  = (const float*)d_in[3];
    const float* b1  = (const float*)d_in[4];
    const float* W2  = (const float*)d_in[5];
    const float* b2  = (const float*)d_in[6];
    const float* Wd1 = (const float*)d_in[7];
    const float* bd1 = (const float*)d_in[8];
    const float* Wd2 = (const float*)d_in[9];
    const float* bd2 = (const float*)d_in[10];
    const float* Wd3 = (const float*)d_in[11];
    const float* bd3 = (const float*)d_in[12];
    const float* Wd4 = (const float*)d_in[13];
    const float* bd4 = (const float*)d_in[14];
    float* out = (float*)d_out;
    char* ws = (char*)d_ws;

    if (ws_size < WS_NEED) {
        hipLaunchKernelGGL(sentinel_kernel, dim3(256), dim3(256), 0, stream, out, out_size);
        return;
    }

    hipLaunchKernelGGL(prep_kernel, dim3((PN5 + 255) / 256), dim3(256), 0, stream,
                       seq_in, W1, b1, W2, b2, ws);

    for (int t = 0; t <= Tn; ++t)
        hipLaunchKernelGGL(step_kernel, dim3(512), dim3(64), 0, stream, lens, ws, t);

    float* h2all = (float*)(ws + OFF_H2ALL);
    float* X1    = (float*)(ws + OFF_X1);
    float* X2 = h2all;   // h2all dead after D1
    float* X3 = X1;      // X1 dead after D2

    hipLaunchKernelGGL(gemm_relu_kernel, dim3(4, 256), dim3(256), 0, stream,
                       h2all, Wd1, bd1, X1, Bn * Tn, 512, 512, 1);
    hipLaunchKernelGGL(gemm_relu_kernel, dim3(4, 256), dim3(256), 0, stream,
                       X1, Wd2, bd2, X2, Bn * Tn, 512, 512, 1);
    hipLaunchKernelGGL(gemm_relu_kernel, dim3(2, 256), dim3(256), 0, stream,
                       X2, Wd3, bd3, X3, Bn * Tn, 256, 512, 1);
    hipLaunchKernelGGL(d4_kernel, dim3((Bn * Tn) / 4), dim3(256), 0, stream,
                       X3, Wd4, bd4, out);
    hipLaunchKernelGGL(loss_kernel, dim3(1), dim3(256), 0, stream,
                       out, tgt, lens, out + (size_t)Bn * Tn * 4);
}